// Round 6
// baseline (507.102 us; speedup 1.0000x reference)
//
#include <hip/hip_runtime.h>
#include <hip/hip_bf16.h>
#include <cstdint>

typedef unsigned short u16;
typedef __attribute__((ext_vector_type(8))) short short8;
typedef __attribute__((ext_vector_type(4))) float f32x4;
typedef __attribute__((ext_vector_type(16))) float f32x16;
typedef __attribute__((ext_vector_type(4))) unsigned short u16x4;

// B=4 R=64 C=64 D=512 H=4 DH=128 S=4096, M = B*S = 16384

__device__ __forceinline__ u16 f2b(float f) {
  uint32_t x = __float_as_uint(f);
  x += 0x7fffu + ((x >> 16) & 1u);
  return (u16)(x >> 16);
}

// RNE f32x4 (scaled) -> 4 packed bf16
__device__ __forceinline__ uint2 pkbf16x4(f32x4 v, float s) {
  uint2 r;
  r.x = (uint32_t)f2b(v[0] * s) | ((uint32_t)f2b(v[1] * s) << 16);
  r.y = (uint32_t)f2b(v[2] * s) | ((uint32_t)f2b(v[3] * s) << 16);
  return r;
}

// v_cvt_pk_bf16_f32: two floats -> packed bf16 pair (RNE)
__device__ __forceinline__ uint32_t cvt2(float a, float b) {
  __hip_bfloat162 t = __float22bfloat162_rn(make_float2(a, b));
  uint32_t r;
  __builtin_memcpy(&r, &t, 4);
  return r;
}

#define LDS_FENCE() asm volatile("s_waitcnt lgkmcnt(0)" ::: "memory")

// ---------------- x fp32 -> bf16 cast ------------------------------------
__global__ __launch_bounds__(256) void xcast(const float* __restrict__ x,
                                             u16* __restrict__ xb) {
  const size_t i = (size_t)(blockIdx.x * 256 + threadIdx.x) * 8;
  const float4 a = *(const float4*)(x + i);
  const float4 b = *(const float4*)(x + i + 4);
  u16x4 lo = {f2b(a.x), f2b(a.y), f2b(a.z), f2b(a.w)};
  u16x4 hi = {f2b(b.x), f2b(b.y), f2b(b.z), f2b(b.w)};
  *(u16x4*)(xb + i) = lo;
  *(u16x4*)(xb + i + 4) = hi;
}

// ---------------- tiled weight transpose + bf16: wT[n][k] = w[k][n] ------
__global__ __launch_bounds__(256) void transpose_all(const float* __restrict__ wq,
                                                     const float* __restrict__ wk,
                                                     const float* __restrict__ wv,
                                                     const float* __restrict__ wo,
                                                     u16* __restrict__ wT,
                                                     u16* __restrict__ woT) {
  __shared__ __align__(16) u16 T[64][68];
  const int mtx = blockIdx.y;
  const float* src = (mtx == 0) ? wq : (mtx == 1) ? wk : (mtx == 2) ? wv : wo;
  u16* dst = (mtx < 3) ? (wT + (size_t)mtx * 262144) : woT;
  const int tr = blockIdx.x >> 3, tc = blockIdx.x & 7;
  const int tid = threadIdx.x;
#pragma unroll
  for (int p = 0; p < 4; ++p) {
    int i = p * 256 + tid;
    int row = i >> 4, c4 = i & 15;
    float4 v = *(const float4*)(src + (size_t)(tr * 64 + row) * 512 + tc * 64 + c4 * 4);
    T[c4 * 4 + 0][row] = f2b(v.x);
    T[c4 * 4 + 1][row] = f2b(v.y);
    T[c4 * 4 + 2][row] = f2b(v.z);
    T[c4 * 4 + 3][row] = f2b(v.w);
  }
  __syncthreads();
#pragma unroll
  for (int p = 0; p < 4; ++p) {
    int i = p * 256 + tid;
    int row = i >> 4, c4 = i & 15;
    *(u16x4*)(dst + (size_t)(tc * 64 + row) * 512 + tr * 64 + c4 * 4) =
        *(const u16x4*)&T[row][c4 * 4];
  }
}

// ---------------- QKV projection GEMM ------------------------------------
__global__ __launch_bounds__(512, 4) void qkv_gemm(const u16* __restrict__ xb,
                                                   const u16* __restrict__ wT_all,
                                                   u16* __restrict__ qbuf,
                                                   u16* __restrict__ kbuf,
                                                   u16* __restrict__ vtbuf) {
  __shared__ __align__(16) u16 smem[128 * 72 + 256 * 72];  // As | Bs, 54 KB
  u16* As = smem;              // [128][72]
  u16* Bs = smem + 128 * 72;   // [256][72]
  const int tid = threadIdx.x;
  const int wave = tid >> 6, lane = tid & 63, quad = lane >> 4, l16 = lane & 15;
  const int wm = wave >> 2, wn = wave & 3;
  const int m0 = blockIdx.x * 128;
  const int which = blockIdx.y >> 1;            // 0=q 1=k 2=v
  const int n0 = (blockIdx.y & 1) * 256;        // dh offset within which
  const u16* wTb = wT_all + (size_t)which * 262144 + (size_t)n0 * 512;

  f32x4 acc[4][4];
  const f32x4 fz = {0.f, 0.f, 0.f, 0.f};
#pragma unroll
  for (int i = 0; i < 4; ++i)
#pragma unroll
    for (int j = 0; j < 4; ++j) acc[i][j] = fz;

  for (int k0 = 0; k0 < 512; k0 += 64) {
#pragma unroll
    for (int p = 0; p < 2; ++p) {
      int i = p * 512 + tid, row = i >> 3, c8 = i & 7;
      uint4 v = *(const uint4*)(xb + (size_t)(m0 + row) * 512 + k0 + c8 * 8);
      *(uint4*)&As[row * 72 + c8 * 8] = v;
    }
#pragma unroll
    for (int p = 0; p < 4; ++p) {
      int i = p * 512 + tid, row = i >> 3, c8 = i & 7;
      uint4 v = *(const uint4*)(wTb + (size_t)row * 512 + k0 + c8 * 8);
      *(uint4*)&Bs[row * 72 + c8 * 8] = v;
    }
    __syncthreads();
#pragma unroll
    for (int ks = 0; ks < 2; ++ks) {
      short8 xf[4], wf[4];
#pragma unroll
      for (int mt = 0; mt < 4; ++mt)
        xf[mt] = *(const short8*)&As[(wm * 64 + mt * 16 + l16) * 72 + ks * 32 + quad * 8];
#pragma unroll
      for (int nt = 0; nt < 4; ++nt)
        wf[nt] = *(const short8*)&Bs[(wn * 64 + nt * 16 + l16) * 72 + ks * 32 + quad * 8];
      if (which < 2) {
#pragma unroll
        for (int mt = 0; mt < 4; ++mt)
#pragma unroll
          for (int nt = 0; nt < 4; ++nt)
            acc[mt][nt] = __builtin_amdgcn_mfma_f32_16x16x32_bf16(wf[nt], xf[mt],
                                                                  acc[mt][nt], 0, 0, 0);
      } else {
#pragma unroll
        for (int mt = 0; mt < 4; ++mt)
#pragma unroll
          for (int nt = 0; nt < 4; ++nt)
            acc[mt][nt] = __builtin_amdgcn_mfma_f32_16x16x32_bf16(xf[mt], wf[nt],
                                                                  acc[mt][nt], 0, 0, 0);
      }
    }
    __syncthreads();
  }
  // After the final barrier each wave owns a private smem slice (3072 u16).
  u16* sw = smem + wave * 3072;
  const int dhg0 = n0 + wn * 64;
  const int h = dhg0 >> 7, dhh0 = dhg0 & 127;
  const int bq = m0 >> 12;
  const int bh = bq * 4 + h;
  const int sl0 = (m0 & 4095) + wm * 64;

  if (which < 2) {
    const float scl = (which == 0) ? 0.08838834764831845f : 1.0f;  // DH^-0.5 on q
    u16* dst = (which == 0) ? qbuf : kbuf;
#pragma unroll
    for (int mt = 0; mt < 4; ++mt) {
      LDS_FENCE();
#pragma unroll
      for (int nt = 0; nt < 4; ++nt)
        *(uint2*)&sw[l16 * 68 + nt * 16 + quad * 4] = pkbf16x4(acc[mt][nt], scl);
      LDS_FENCE();
#pragma unroll
      for (int p = 0; p < 2; ++p) {
        const int sr = p * 8 + (lane >> 3), dl = (lane & 7) * 8;
        uint4 v = *(const uint4*)&sw[sr * 68 + dl];
        const int sl = sl0 + mt * 16 + sr;
        *(uint4*)(dst + ((size_t)(bh * 4096 + sl)) * 128 + dhh0 + dl) = v;
      }
    }
  } else {
#pragma unroll
    for (int p2 = 0; p2 < 2; ++p2) {
      LDS_FENCE();
#pragma unroll
      for (int m2 = 0; m2 < 2; ++m2) {
        const int mt = p2 * 2 + m2;
#pragma unroll
        for (int nt = 0; nt < 4; ++nt)
          *(uint2*)&sw[(nt * 16 + l16) * 36 + m2 * 16 + quad * 4] =
              pkbf16x4(acc[mt][nt], 1.0f);
      }
      LDS_FENCE();
#pragma unroll
      for (int j = 0; j < 4; ++j) {
        const int dl = j * 16 + (lane >> 2), so = (lane & 3) * 8;
        uint4 v = *(const uint4*)&sw[dl * 36 + so];
        const int sl = sl0 + p2 * 32 + so;
        *(uint4*)(vtbuf + ((size_t)(bh * 128 + dhh0 + dl)) * 4096 + sl) = v;
      }
    }
  }
}

// ---------------- causal flash attention, 32x32x16 MFMA ------------------
// 512 threads, 128 q/block. Wave (kh=w>>2, qq=w&3):
//   S-phase: one 32keys x 32q tile, Q frags persistent in registers.
//   PV-phase: O^T tile 64dh(kh half) x 32q from full-64-key P.
// P handoff [q][key] in LDS (stride 72 -> conflict-free b128), 3 barriers/it.
__global__ __launch_bounds__(512, 4) void attn(const u16* __restrict__ qbuf,
                                               const u16* __restrict__ kbuf,
                                               const u16* __restrict__ vtbuf,
                                               const float* __restrict__ rel_row,
                                               const float* __restrict__ rel_col,
                                               u16* __restrict__ obuf) {
  __shared__ __align__(16) u16 Ks[64][136];   // [key][dh], 68 dw = 4 mod 32
  __shared__ __align__(16) u16 Vt[128][72];   // [dh][key], 36 dw = 4 mod 32
  __shared__ __align__(16) u16 Pl[128][72];   // [q][key],  36 dw = 4 mod 32
  __shared__ float rcol[128];
  __shared__ float rrow[128];
  __shared__ float Lpart[2][128];

  const int tid = threadIdx.x;
  const int wave = tid >> 6, lane = tid & 63;
  const int l31 = lane & 31, lhi = lane >> 5;
  const int qq = wave & 3, kh = wave >> 2;     // kh doubles as dh-half in PV
  const int bh = blockIdx.x & 15;
  const int qt = (blockIdx.x < 256) ? (31 - (blockIdx.x >> 4))
                                    : ((blockIdx.x >> 4) - 16);
  const int b = bh >> 2, h = bh & 3;

  if (tid < 128) rcol[tid] = rel_col[h * 128 + tid];
  else if (tid < 256) rrow[tid - 128] = rel_row[h * 128 + (tid - 128)];

  const int q_glob = qt * 128 + qq * 32 + l31;
  const int qr = 2 * qt + (qq >> 1);          // raster row of this wave's q
  const int qc = (qq & 1) * 32 + l31;         // q mod 64

  // persistent Q B-frags: B[k=dh][n=q], k-chunk c: dh = c*16 + lhi*8 + j
  const u16* qrow = qbuf + ((size_t)bh * 4096 + q_glob) * 128;
  short8 qf[8];
#pragma unroll
  for (int c = 0; c < 8; ++c) qf[c] = *(const short8*)(qrow + c * 16 + lhi * 8);

  __syncthreads();   // rcol/rrow visible

  const float LOG2E = 1.4426950408889634f;
  // key_local(r) = (r&3) + 8*(r>>2) + 4*lhi + kh*32  (kt-invariant col bias)
  float rc2[16];
#pragma unroll
  for (int r = 0; r < 16; ++r) {
    const int kl = (r & 3) + 8 * (r >> 2) + 4 * lhi + kh * 32;
    rc2[r] = rcol[63 + kl - qc] * LOG2E;
  }

  f32x16 oacc0, oacc1;
#pragma unroll
  for (int i = 0; i < 16; ++i) { oacc0[i] = 0.f; oacc1[i] = 0.f; }
  float l_run = 0.0f;

  const u16* kbase = kbuf + (size_t)bh * 4096 * 128;
  const u16* vbase = vtbuf + (size_t)bh * 128 * 4096;
  const int kr = tid >> 4, kc8 = (tid & 15) * 8;   // K staging coords
  const int vr = tid >> 3, vc8 = (tid & 7) * 8;    // V staging coords

  uint4 kreg0, kreg1, vreg0, vreg1;
  kreg0 = *(const uint4*)(kbase + kr * 128 + kc8);
  kreg1 = *(const uint4*)(kbase + (32 + kr) * 128 + kc8);
  vreg0 = *(const uint4*)(vbase + (size_t)vr * 4096 + vc8);
  vreg1 = *(const uint4*)(vbase + (size_t)(64 + vr) * 4096 + vc8);

  const int ktmax = 2 * qt + 1;
  for (int kt = 0; kt <= ktmax; ++kt) {
    __syncthreads();   // prev iteration's PV reads done
    *(uint4*)&Ks[kr][kc8] = kreg0;
    *(uint4*)&Ks[32 + kr][kc8] = kreg1;
    *(uint4*)&Vt[vr][vc8] = vreg0;
    *(uint4*)&Vt[64 + vr][vc8] = vreg1;
    __syncthreads();
    if (kt < ktmax) {   // prefetch next tile under compute
      const u16* ksrc = kbase + (kt + 1) * 64 * 128;
      const u16* vsrc = vbase + (kt + 1) * 64;
      kreg0 = *(const uint4*)(ksrc + kr * 128 + kc8);
      kreg1 = *(const uint4*)(ksrc + (32 + kr) * 128 + kc8);
      vreg0 = *(const uint4*)(vsrc + (size_t)vr * 4096 + vc8);
      vreg1 = *(const uint4*)(vsrc + (size_t)(64 + vr) * 4096 + vc8);
    }

    const bool active = (kt <= qr);
    if (active) {
      // S^T tile: A=K[m=key 32(kh)][k=dh], B=Q -> C col=q, row=key
      f32x16 sacc;
#pragma unroll
      for (int i = 0; i < 16; ++i) sacc[i] = 0.f;
#pragma unroll
      for (int c = 0; c < 8; ++c) {
        short8 kf = *(const short8*)&Ks[kh * 32 + l31][c * 16 + lhi * 8];
        sacc = __builtin_amdgcn_mfma_f32_32x32x16_bf16(kf, qf[c], sacc, 0, 0, 0);
      }

      const float browl = rrow[63 + kt - qr] * LOG2E;
      float p[16];
#pragma unroll
      for (int r = 0; r < 16; ++r)
        p[r] = __builtin_amdgcn_exp2f(fmaf(sacc[r], LOG2E, rc2[r] + browl));
      if (kt == qr) {
#pragma unroll
        for (int r = 0; r < 16; ++r) {
          const int kl = (r & 3) + 8 * (r >> 2) + 4 * lhi + kh * 32;
          if (kl > qc) p[r] = 0.0f;
        }
      }
#pragma unroll
      for (int r = 0; r < 16; ++r) l_run += p[r];
      // P write: reg quads 4g..4g+3 = keys kh*32 + 8g + 4*lhi + {0..3}
#pragma unroll
      for (int g = 0; g < 4; ++g) {
        uint2 w;
        w.x = cvt2(p[4 * g], p[4 * g + 1]);
        w.y = cvt2(p[4 * g + 2], p[4 * g + 3]);
        *(uint2*)&Pl[qq * 32 + l31][kh * 32 + g * 8 + lhi * 4] = w;
      }
    }
    __syncthreads();   // P ready
    if (active) {
      // O^T += V^T . P^T : A=Vt[m=dh][k=key], B=Pl[q][key]
#pragma unroll
      for (int kc = 0; kc < 4; ++kc) {
        short8 pf = *(const short8*)&Pl[qq * 32 + l31][kc * 16 + lhi * 8];
        short8 vf0 = *(const short8*)&Vt[kh * 64 + l31][kc * 16 + lhi * 8];
        short8 vf1 = *(const short8*)&Vt[kh * 64 + 32 + l31][kc * 16 + lhi * 8];
        oacc0 = __builtin_amdgcn_mfma_f32_32x32x16_bf16(vf0, pf, oacc0, 0, 0, 0);
        oacc1 = __builtin_amdgcn_mfma_f32_32x32x16_bf16(vf1, pf, oacc1, 0, 0, 0);
      }
    }
  }

  // epilogue: combine l across lane^32 and the kh wave pair, then store O
  l_run += __shfl_xor(l_run, 32);
  if (lane < 32) Lpart[kh][qq * 32 + l31] = l_run;
  __syncthreads();
  const float inv_l = 1.0f / (Lpart[0][qq * 32 + l31] + Lpart[1][qq * 32 + l31]);

  u16* orow = obuf + ((size_t)b * 4096 + q_glob) * 512 + h * 128 + kh * 64;
#pragma unroll
  for (int t = 0; t < 2; ++t) {
    const f32x16 o = t ? oacc1 : oacc0;
#pragma unroll
    for (int g = 0; g < 4; ++g) {
      uint2 w;
      w.x = cvt2(o[4 * g] * inv_l, o[4 * g + 1] * inv_l);
      w.y = cvt2(o[4 * g + 2] * inv_l, o[4 * g + 3] * inv_l);
      *(uint2*)(orow + t * 32 + g * 8 + lhi * 4) = w;
    }
  }
}

// ---------------- output projection GEMM ---------------------------------
__global__ __launch_bounds__(512, 4) void out_gemm(const u16* __restrict__ obuf,
                                                   const u16* __restrict__ woT,
                                                   float* __restrict__ out) {
  __shared__ __align__(16) u16 smem[128 * 72 + 256 * 72];
  u16* As = smem;              // [128][72] obuf rows (s)
  u16* Bs = smem + 128 * 72;   // [256][72] woT rows (d)
  const int tid = threadIdx.x;
  const int wave = tid >> 6, lane = tid & 63, quad = lane >> 4, l16 = lane & 15;
  const int wm = wave >> 2, wn = wave & 3;
  const int m0 = blockIdx.x * 128;
  const int n0 = blockIdx.y * 256;

  f32x4 acc[4][4];
  const f32x4 fz = {0.f, 0.f, 0.f, 0.f};
#pragma unroll
  for (int i = 0; i < 4; ++i)
#pragma unroll
    for (int j = 0; j < 4; ++j) acc[i][j] = fz;

  for (int k0 = 0; k0 < 512; k0 += 64) {
#pragma unroll
    for (int p = 0; p < 2; ++p) {
      int i = p * 512 + tid, row = i >> 3, c8 = i & 7;
      uint4 v = *(const uint4*)(obuf + (size_t)(m0 + row) * 512 + k0 + c8 * 8);
      *(uint4*)&As[row * 72 + c8 * 8] = v;
    }
#pragma unroll
    for (int p = 0; p < 4; ++p) {
      int i = p * 512 + tid, row = i >> 3, c8 = i & 7;
      uint4 v = *(const uint4*)(woT + (size_t)(n0 + row) * 512 + k0 + c8 * 8);
      *(uint4*)&Bs[row * 72 + c8 * 8] = v;
    }
    __syncthreads();
#pragma unroll
    for (int ks = 0; ks < 2; ++ks) {
      short8 of[4], wf[4];
#pragma unroll
      for (int mt = 0; mt < 4; ++mt)
        of[mt] = *(const short8*)&As[(wm * 64 + mt * 16 + l16) * 72 + ks * 32 + quad * 8];
#pragma unroll
      for (int nt = 0; nt < 4; ++nt)
        wf[nt] = *(const short8*)&Bs[(wn * 64 + nt * 16 + l16) * 72 + ks * 32 + quad * 8];
#pragma unroll
      for (int mt = 0; mt < 4; ++mt)
#pragma unroll
        for (int nt = 0; nt < 4; ++nt)
          acc[mt][nt] = __builtin_amdgcn_mfma_f32_16x16x32_bf16(wf[nt], of[mt],
                                                                acc[mt][nt], 0, 0, 0);
    }
    __syncthreads();
  }

  float* swf = (float*)smem + wave * 1536;   // per-wave [16 s][68 d] f32
#pragma unroll
  for (int mt = 0; mt < 4; ++mt) {
    LDS_FENCE();
#pragma unroll
    for (int nt = 0; nt < 4; ++nt)
      *(f32x4*)&swf[l16 * 68 + nt * 16 + quad * 4] = acc[mt][nt];
    LDS_FENCE();
#pragma unroll
    for (int p = 0; p < 4; ++p) {
      const int sr = p * 4 + (lane >> 4), dl = l16 * 4;
      float4 v = *(const float4*)&swf[sr * 68 + dl];
      const int s = m0 + wm * 64 + mt * 16 + sr;
      *(float4*)(out + (size_t)s * 512 + n0 + wn * 64 + dl) = v;
    }
  }
}

// ---------------- launch --------------------------------------------------
extern "C" void kernel_launch(void* const* d_in, const int* in_sizes, int n_in,
                              void* d_out, int out_size, void* d_ws, size_t ws_size,
                              hipStream_t stream) {
  const float* x       = (const float*)d_in[0];
  const float* wq      = (const float*)d_in[1];
  const float* wk      = (const float*)d_in[2];
  const float* wv      = (const float*)d_in[3];
  const float* wo      = (const float*)d_in[4];
  const float* rel_row = (const float*)d_in[5];
  const float* rel_col = (const float*)d_in[6];
  float* out = (float*)d_out;

  char* ws = (char*)d_ws;
  u16* wT    = (u16*)(ws);                               // 3 * 512*512 bf16
  u16* woT   = (u16*)(ws + 1572864);                     // 512*512 bf16
  u16* qbuf  = (u16*)(ws + 2097152);                     // 16 MiB
  u16* kbuf  = (u16*)(ws + 2097152 + 16777216);          // 16 MiB
  u16* vtbuf = (u16*)(ws + 2097152 + 2 * 16777216);      // 16 MiB
  u16* obuf  = (u16*)(ws + 2097152 + 3 * 16777216);      // 16 MiB
  u16* xb    = obuf;  // xb consumed by qkv_gemm before attn writes obuf

  xcast<<<4096, 256, 0, stream>>>(x, xb);
  transpose_all<<<dim3(64, 4), 256, 0, stream>>>(wq, wk, wv, wo, wT, woT);
  qkv_gemm<<<dim3(128, 6), 512, 0, stream>>>(xb, wT, qbuf, kbuf, vtbuf);
  attn<<<512, 512, 0, stream>>>(qbuf, kbuf, vtbuf, rel_row, rel_col, obuf);
  out_gemm<<<dim3(128, 2), 512, 0, stream>>>(obuf, woT, out);
}

// Round 7
// 347.655 us; speedup vs baseline: 1.4586x; 1.4586x over previous
//
#include <hip/hip_runtime.h>
#include <hip/hip_bf16.h>
#include <cstdint>

typedef unsigned short u16;
typedef __attribute__((ext_vector_type(8))) short short8;
typedef __attribute__((ext_vector_type(4))) float f32x4;
typedef __attribute__((ext_vector_type(16))) float f32x16;
typedef __attribute__((ext_vector_type(4))) unsigned short u16x4;

// B=4 R=64 C=64 D=512 H=4 DH=128 S=4096, M = B*S = 16384

__device__ __forceinline__ u16 f2b(float f) {
  uint32_t x = __float_as_uint(f);
  x += 0x7fffu + ((x >> 16) & 1u);
  return (u16)(x >> 16);
}

// RNE f32x4 (scaled) -> 4 packed bf16
__device__ __forceinline__ uint2 pkbf16x4(f32x4 v, float s) {
  uint2 r;
  r.x = (uint32_t)f2b(v[0] * s) | ((uint32_t)f2b(v[1] * s) << 16);
  r.y = (uint32_t)f2b(v[2] * s) | ((uint32_t)f2b(v[3] * s) << 16);
  return r;
}

__device__ __forceinline__ uint32_t cvt2(float a, float b) {
  __hip_bfloat162 t = __float22bfloat162_rn(make_float2(a, b));
  uint32_t r;
  __builtin_memcpy(&r, &t, 4);
  return r;
}

#define LDS_FENCE() asm volatile("s_waitcnt lgkmcnt(0)" ::: "memory")

// ---------------- x fp32 -> bf16 cast ------------------------------------
__global__ __launch_bounds__(256) void xcast(const float* __restrict__ x,
                                             u16* __restrict__ xb) {
  const size_t i = (size_t)(blockIdx.x * 256 + threadIdx.x) * 8;
  const float4 a = *(const float4*)(x + i);
  const float4 b = *(const float4*)(x + i + 4);
  u16x4 lo = {f2b(a.x), f2b(a.y), f2b(a.z), f2b(a.w)};
  u16x4 hi = {f2b(b.x), f2b(b.y), f2b(b.z), f2b(b.w)};
  *(u16x4*)(xb + i) = lo;
  *(u16x4*)(xb + i + 4) = hi;
}

// ---------------- tiled weight transpose + bf16: wT[n][k] = w[k][n] ------
__global__ __launch_bounds__(256) void transpose_all(const float* __restrict__ wq,
                                                     const float* __restrict__ wk,
                                                     const float* __restrict__ wv,
                                                     const float* __restrict__ wo,
                                                     u16* __restrict__ wT,
                                                     u16* __restrict__ woT) {
  __shared__ __align__(16) u16 T[64][68];
  const int mtx = blockIdx.y;
  const float* src = (mtx == 0) ? wq : (mtx == 1) ? wk : (mtx == 2) ? wv : wo;
  u16* dst = (mtx < 3) ? (wT + (size_t)mtx * 262144) : woT;
  const int tr = blockIdx.x >> 3, tc = blockIdx.x & 7;
  const int tid = threadIdx.x;
#pragma unroll
  for (int p = 0; p < 4; ++p) {
    int i = p * 256 + tid;
    int row = i >> 4, c4 = i & 15;
    float4 v = *(const float4*)(src + (size_t)(tr * 64 + row) * 512 + tc * 64 + c4 * 4);
    T[c4 * 4 + 0][row] = f2b(v.x);
    T[c4 * 4 + 1][row] = f2b(v.y);
    T[c4 * 4 + 2][row] = f2b(v.z);
    T[c4 * 4 + 3][row] = f2b(v.w);
  }
  __syncthreads();
#pragma unroll
  for (int p = 0; p < 4; ++p) {
    int i = p * 256 + tid;
    int row = i >> 4, c4 = i & 15;
    *(u16x4*)(dst + (size_t)(tc * 64 + row) * 512 + tr * 64 + c4 * 4) =
        *(const u16x4*)&T[row][c4 * 4];
  }
}

// ---------------- QKV projection GEMM ------------------------------------
// launch_bounds (512,2): 2nd arg MUST stay 2 — (512,4) caps unified
// VGPR+AGPR at 128/thread and the 64-AGPR accumulator forces scratch spill
// (measured rounds 4/6: ~650 MB HBM spill writes, 2.5x slowdown).
__global__ __launch_bounds__(512, 2) void qkv_gemm(const u16* __restrict__ xb,
                                                   const u16* __restrict__ wT_all,
                                                   u16* __restrict__ qbuf,
                                                   u16* __restrict__ kbuf,
                                                   u16* __restrict__ vtbuf) {
  __shared__ __align__(16) u16 smem[128 * 72 + 256 * 72];  // As | Bs, 54 KB
  u16* As = smem;              // [128][72]
  u16* Bs = smem + 128 * 72;   // [256][72]
  const int tid = threadIdx.x;
  const int wave = tid >> 6, lane = tid & 63, quad = lane >> 4, l16 = lane & 15;
  const int wm = wave >> 2, wn = wave & 3;
  const int m0 = blockIdx.x * 128;
  const int which = blockIdx.y >> 1;            // 0=q 1=k 2=v
  const int n0 = (blockIdx.y & 1) * 256;        // dh offset within which
  const u16* wTb = wT_all + (size_t)which * 262144 + (size_t)n0 * 512;

  f32x4 acc[4][4];
  const f32x4 fz = {0.f, 0.f, 0.f, 0.f};
#pragma unroll
  for (int i = 0; i < 4; ++i)
#pragma unroll
    for (int j = 0; j < 4; ++j) acc[i][j] = fz;

  for (int k0 = 0; k0 < 512; k0 += 64) {
#pragma unroll
    for (int p = 0; p < 2; ++p) {
      int i = p * 512 + tid, row = i >> 3, c8 = i & 7;
      uint4 v = *(const uint4*)(xb + (size_t)(m0 + row) * 512 + k0 + c8 * 8);
      *(uint4*)&As[row * 72 + c8 * 8] = v;
    }
#pragma unroll
    for (int p = 0; p < 4; ++p) {
      int i = p * 512 + tid, row = i >> 3, c8 = i & 7;
      uint4 v = *(const uint4*)(wTb + (size_t)row * 512 + k0 + c8 * 8);
      *(uint4*)&Bs[row * 72 + c8 * 8] = v;
    }
    __syncthreads();
#pragma unroll
    for (int ks = 0; ks < 2; ++ks) {
      short8 xf[4], wf[4];
#pragma unroll
      for (int mt = 0; mt < 4; ++mt)
        xf[mt] = *(const short8*)&As[(wm * 64 + mt * 16 + l16) * 72 + ks * 32 + quad * 8];
#pragma unroll
      for (int nt = 0; nt < 4; ++nt)
        wf[nt] = *(const short8*)&Bs[(wn * 64 + nt * 16 + l16) * 72 + ks * 32 + quad * 8];
      if (which < 2) {
#pragma unroll
        for (int mt = 0; mt < 4; ++mt)
#pragma unroll
          for (int nt = 0; nt < 4; ++nt)
            acc[mt][nt] = __builtin_amdgcn_mfma_f32_16x16x32_bf16(wf[nt], xf[mt],
                                                                  acc[mt][nt], 0, 0, 0);
      } else {
#pragma unroll
        for (int mt = 0; mt < 4; ++mt)
#pragma unroll
          for (int nt = 0; nt < 4; ++nt)
            acc[mt][nt] = __builtin_amdgcn_mfma_f32_16x16x32_bf16(xf[mt], wf[nt],
                                                                  acc[mt][nt], 0, 0, 0);
      }
    }
    __syncthreads();
  }
  // After the final barrier each wave owns a private smem slice (3072 u16).
  u16* sw = smem + wave * 3072;
  const int dhg0 = n0 + wn * 64;
  const int h = dhg0 >> 7, dhh0 = dhg0 & 127;
  const int bq = m0 >> 12;
  const int bh = bq * 4 + h;
  const int sl0 = (m0 & 4095) + wm * 64;

  if (which < 2) {
    const float scl = (which == 0) ? 0.08838834764831845f : 1.0f;  // DH^-0.5 on q
    u16* dst = (which == 0) ? qbuf : kbuf;
#pragma unroll
    for (int mt = 0; mt < 4; ++mt) {
      LDS_FENCE();
#pragma unroll
      for (int nt = 0; nt < 4; ++nt)
        *(uint2*)&sw[l16 * 68 + nt * 16 + quad * 4] = pkbf16x4(acc[mt][nt], scl);
      LDS_FENCE();
#pragma unroll
      for (int p = 0; p < 2; ++p) {
        const int sr = p * 8 + (lane >> 3), dl = (lane & 7) * 8;
        uint4 v = *(const uint4*)&sw[sr * 68 + dl];
        const int sl = sl0 + mt * 16 + sr;
        *(uint4*)(dst + ((size_t)(bh * 4096 + sl)) * 128 + dhh0 + dl) = v;
      }
    }
  } else {
#pragma unroll
    for (int p2 = 0; p2 < 2; ++p2) {
      LDS_FENCE();
#pragma unroll
      for (int m2 = 0; m2 < 2; ++m2) {
        const int mt = p2 * 2 + m2;
#pragma unroll
        for (int nt = 0; nt < 4; ++nt)
          *(uint2*)&sw[(nt * 16 + l16) * 36 + m2 * 16 + quad * 4] =
              pkbf16x4(acc[mt][nt], 1.0f);
      }
      LDS_FENCE();
#pragma unroll
      for (int j = 0; j < 4; ++j) {
        const int dl = j * 16 + (lane >> 2), so = (lane & 3) * 8;
        uint4 v = *(const uint4*)&sw[dl * 36 + so];
        const int sl = sl0 + p2 * 32 + so;
        *(uint4*)(vtbuf + ((size_t)(bh * 128 + dhh0 + dl)) * 4096 + sl) = v;
      }
    }
  }
}

// ---------------- causal flash attention, 32 q/wave, 32x32x16 MFMA -------
// 256 threads, 4 waves, 128 q/block. Round-5 skeleton (2 barriers/iter,
// register prefetch, wave-private P) with 2x q per wave: K/V LDS fragment
// reads amortize over 32 queries -> ~0.6x LDS-port cycles per query.
__global__ __launch_bounds__(256, 2) void attn(const u16* __restrict__ qbuf,
                                               const u16* __restrict__ kbuf,
                                               const u16* __restrict__ vtbuf,
                                               const float* __restrict__ rel_row,
                                               const float* __restrict__ rel_col,
                                               u16* __restrict__ obuf) {
  __shared__ __align__(16) u16 Ks[64][136];    // [key][dh]
  __shared__ __align__(16) u16 Vt[128][72];    // [dh][key]
  __shared__ __align__(16) u16 Pl[4][32][72];  // per-wave [q][key]
  __shared__ float rcol[128];
  __shared__ float rrow[64];

  const int tid = threadIdx.x;
  const int wave = tid >> 6, lane = tid & 63;
  const int l31 = lane & 31, lhi = lane >> 5;
  const int bh = blockIdx.x & 15;
  // balanced pairing: block c (heavy) shares a CU with block c+256 (light)
  const int qt = (blockIdx.x < 256) ? (31 - (blockIdx.x >> 4))
                                    : ((blockIdx.x >> 4) - 16);
  const int b = bh >> 2, h = bh & 3;

  if (tid < 128) rcol[tid] = rel_col[h * 128 + tid];
  else if (tid < 192) rrow[tid - 128] = rel_row[h * 128 + (tid - 128)];

  const int q_loc = wave * 32 + l31;           // 0..127
  const int q_glob = qt * 128 + q_loc;
  const int qr = 2 * qt + (wave >> 1);         // raster row (uniform per wave)
  const int qc = q_loc & 63;

  // persistent Q B-frags: B[k=dh][n=q], lane n=l31, k = c*16 + lhi*8 + j
  const u16* qrow = qbuf + ((size_t)bh * 4096 + q_glob) * 128;
  short8 qf[8];
#pragma unroll
  for (int c = 0; c < 8; ++c) qf[c] = *(const short8*)(qrow + c * 16 + lhi * 8);

  __syncthreads();   // rcol/rrow visible

  const float LOG2E = 1.4426950408889634f;
  // kt-invariant column bias; key_local = kk*32 + (r&3) + 8*(r>>2) + 4*lhi
  float rc2[2][16];
#pragma unroll
  for (int kk = 0; kk < 2; ++kk)
#pragma unroll
    for (int r = 0; r < 16; ++r) {
      const int kl = kk * 32 + (r & 3) + 8 * (r >> 2) + 4 * lhi;
      rc2[kk][r] = rcol[63 + kl - qc] * LOG2E;
    }

  f32x16 oacc[4];
#pragma unroll
  for (int mt = 0; mt < 4; ++mt)
#pragma unroll
    for (int i = 0; i < 16; ++i) oacc[mt][i] = 0.f;
  float l_run = 0.0f;

  const u16* kbase = kbuf + (size_t)bh * 4096 * 128;
  const u16* vbase = vtbuf + (size_t)bh * 128 * 4096;
  const int krw = tid >> 4, kcl = (tid & 15) * 8;   // K staging: 16 rows/pass
  const int vrw = tid >> 3, vcl = (tid & 7) * 8;    // V staging: 32 rows/pass

  uint4 kreg[4], vreg[4];
#pragma unroll
  for (int p = 0; p < 4; ++p) {
    kreg[p] = *(const uint4*)(kbase + (p * 16 + krw) * 128 + kcl);
    vreg[p] = *(const uint4*)(vbase + (size_t)(p * 32 + vrw) * 4096 + vcl);
  }

  const int ktmax = 2 * qt + 1;
  for (int kt = 0; kt <= ktmax; ++kt) {
    __syncthreads();   // all waves done reading previous LDS tiles
#pragma unroll
    for (int p = 0; p < 4; ++p) {
      *(uint4*)&Ks[p * 16 + krw][kcl] = kreg[p];
      *(uint4*)&Vt[p * 32 + vrw][vcl] = vreg[p];
    }
    __syncthreads();
    if (kt < ktmax) {   // prefetch next tile; latency hides under compute
      const u16* ksrc = kbase + (kt + 1) * 64 * 128;
      const u16* vsrc = vbase + (kt + 1) * 64;
#pragma unroll
      for (int p = 0; p < 4; ++p) {
        kreg[p] = *(const uint4*)(ksrc + (p * 16 + krw) * 128 + kcl);
        vreg[p] = *(const uint4*)(vsrc + (size_t)(p * 32 + vrw) * 4096 + vcl);
      }
    }

    if (kt <= qr) {
      // S^T: two 32key x 32q tiles. A=K[m=key][k=dh], B=Q -> C lane=q
      f32x16 sacc0, sacc1;
#pragma unroll
      for (int i = 0; i < 16; ++i) { sacc0[i] = 0.f; sacc1[i] = 0.f; }
#pragma unroll
      for (int c = 0; c < 8; ++c) {
        short8 kf0 = *(const short8*)&Ks[l31][c * 16 + lhi * 8];
        short8 kf1 = *(const short8*)&Ks[32 + l31][c * 16 + lhi * 8];
        sacc0 = __builtin_amdgcn_mfma_f32_32x32x16_bf16(kf0, qf[c], sacc0, 0, 0, 0);
        sacc1 = __builtin_amdgcn_mfma_f32_32x32x16_bf16(kf1, qf[c], sacc1, 0, 0, 0);
      }

      const float browl = rrow[63 + kt - qr] * LOG2E;
      const bool diag = (kt == qr);
#pragma unroll
      for (int kk = 0; kk < 2; ++kk) {
        const f32x16 sa = kk ? sacc1 : sacc0;
        float pv[16];
#pragma unroll
        for (int r = 0; r < 16; ++r)
          pv[r] = exp2f(fmaf(sa[r], LOG2E, rc2[kk][r] + browl));
        if (diag) {
#pragma unroll
          for (int r = 0; r < 16; ++r) {
            const int kl = kk * 32 + (r & 3) + 8 * (r >> 2) + 4 * lhi;
            if (kl > qc) pv[r] = 0.0f;
          }
        }
#pragma unroll
        for (int r = 0; r < 16; ++r) l_run += pv[r];
#pragma unroll
        for (int g = 0; g < 4; ++g) {
          uint2 w;
          w.x = cvt2(pv[4 * g], pv[4 * g + 1]);
          w.y = cvt2(pv[4 * g + 2], pv[4 * g + 3]);
          *(uint2*)&Pl[wave][l31][kk * 32 + g * 8 + lhi * 4] = w;
        }
      }
      LDS_FENCE();   // wave-private P visible to own reads

      // O^T += V^T . P^T : A=Vt[m=dh][k=key], B=Pl[q][key], lane=q
#pragma unroll
      for (int ks = 0; ks < 4; ++ks) {
        short8 pf = *(const short8*)&Pl[wave][l31][ks * 16 + lhi * 8];
#pragma unroll
        for (int mt = 0; mt < 4; ++mt) {
          short8 vf = *(const short8*)&Vt[mt * 32 + l31][ks * 16 + lhi * 8];
          oacc[mt] = __builtin_amdgcn_mfma_f32_32x32x16_bf16(vf, pf, oacc[mt], 0, 0, 0);
        }
      }
    }
  }

  // epilogue: l covers 32 keys/lane per iter; other half at lane^32
  l_run += __shfl_xor(l_run, 32);
  const float inv_l = 1.0f / l_run;
  u16* orow = obuf + ((size_t)b * 4096 + q_glob) * 512 + h * 128;
#pragma unroll
  for (int mt = 0; mt < 4; ++mt)
#pragma unroll
    for (int g = 0; g < 4; ++g) {
      uint2 w;
      w.x = cvt2(oacc[mt][4 * g] * inv_l, oacc[mt][4 * g + 1] * inv_l);
      w.y = cvt2(oacc[mt][4 * g + 2] * inv_l, oacc[mt][4 * g + 3] * inv_l);
      *(uint2*)(orow + mt * 32 + g * 8 + lhi * 4) = w;
    }
}

// ---------------- output projection GEMM ---------------------------------
// (512,2) — see qkv_gemm note on the spill cliff at (512,4).
__global__ __launch_bounds__(512, 2) void out_gemm(const u16* __restrict__ obuf,
                                                   const u16* __restrict__ woT,
                                                   float* __restrict__ out) {
  __shared__ __align__(16) u16 smem[128 * 72 + 256 * 72];
  u16* As = smem;              // [128][72] obuf rows (s)
  u16* Bs = smem + 128 * 72;   // [256][72] woT rows (d)
  const int tid = threadIdx.x;
  const int wave = tid >> 6, lane = tid & 63, quad = lane >> 4, l16 = lane & 15;
  const int wm = wave >> 2, wn = wave & 3;
  const int m0 = blockIdx.x * 128;
  const int n0 = blockIdx.y * 256;

  f32x4 acc[4][4];
  const f32x4 fz = {0.f, 0.f, 0.f, 0.f};
#pragma unroll
  for (int i = 0; i < 4; ++i)
#pragma unroll
    for (int j = 0; j < 4; ++j) acc[i][j] = fz;

  for (int k0 = 0; k0 < 512; k0 += 64) {
#pragma unroll
    for (int p = 0; p < 2; ++p) {
      int i = p * 512 + tid, row = i >> 3, c8 = i & 7;
      uint4 v = *(const uint4*)(obuf + (size_t)(m0 + row) * 512 + k0 + c8 * 8);
      *(uint4*)&As[row * 72 + c8 * 8] = v;
    }
#pragma unroll
    for (int p = 0; p < 4; ++p) {
      int i = p * 512 + tid, row = i >> 3, c8 = i & 7;
      uint4 v = *(const uint4*)(woT + (size_t)(n0 + row) * 512 + k0 + c8 * 8);
      *(uint4*)&Bs[row * 72 + c8 * 8] = v;
    }
    __syncthreads();
#pragma unroll
    for (int ks = 0; ks < 2; ++ks) {
      short8 of[4], wf[4];
#pragma unroll
      for (int mt = 0; mt < 4; ++mt)
        of[mt] = *(const short8*)&As[(wm * 64 + mt * 16 + l16) * 72 + ks * 32 + quad * 8];
#pragma unroll
      for (int nt = 0; nt < 4; ++nt)
        wf[nt] = *(const short8*)&Bs[(wn * 64 + nt * 16 + l16) * 72 + ks * 32 + quad * 8];
#pragma unroll
      for (int mt = 0; mt < 4; ++mt)
#pragma unroll
        for (int nt = 0; nt < 4; ++nt)
          acc[mt][nt] = __builtin_amdgcn_mfma_f32_16x16x32_bf16(wf[nt], of[mt],
                                                                acc[mt][nt], 0, 0, 0);
    }
    __syncthreads();
  }

  float* swf = (float*)smem + wave * 1536;   // per-wave [16 s][68 d] f32
#pragma unroll
  for (int mt = 0; mt < 4; ++mt) {
    LDS_FENCE();
#pragma unroll
    for (int nt = 0; nt < 4; ++nt)
      *(f32x4*)&swf[l16 * 68 + nt * 16 + quad * 4] = acc[mt][nt];
    LDS_FENCE();
#pragma unroll
    for (int p = 0; p < 4; ++p) {
      const int sr = p * 4 + (lane >> 4), dl = l16 * 4;
      float4 v = *(const float4*)&swf[sr * 68 + dl];
      const int s = m0 + wm * 64 + mt * 16 + sr;
      *(float4*)(out + (size_t)s * 512 + n0 + wn * 64 + dl) = v;
    }
  }
}

// ---------------- launch --------------------------------------------------
extern "C" void kernel_launch(void* const* d_in, const int* in_sizes, int n_in,
                              void* d_out, int out_size, void* d_ws, size_t ws_size,
                              hipStream_t stream) {
  const float* x       = (const float*)d_in[0];
  const float* wq      = (const float*)d_in[1];
  const float* wk      = (const float*)d_in[2];
  const float* wv      = (const float*)d_in[3];
  const float* wo      = (const float*)d_in[4];
  const float* rel_row = (const float*)d_in[5];
  const float* rel_col = (const float*)d_in[6];
  float* out = (float*)d_out;

  char* ws = (char*)d_ws;
  u16* wT    = (u16*)(ws);                               // 3 * 512*512 bf16
  u16* woT   = (u16*)(ws + 1572864);                     // 512*512 bf16
  u16* qbuf  = (u16*)(ws + 2097152);                     // 16 MiB
  u16* kbuf  = (u16*)(ws + 2097152 + 16777216);          // 16 MiB
  u16* vtbuf = (u16*)(ws + 2097152 + 2 * 16777216);      // 16 MiB
  u16* obuf  = (u16*)(ws + 2097152 + 3 * 16777216);      // 16 MiB
  u16* xb    = obuf;  // xb consumed by qkv_gemm before attn writes obuf

  xcast<<<4096, 256, 0, stream>>>(x, xb);
  transpose_all<<<dim3(64, 4), 256, 0, stream>>>(wq, wk, wv, wo, wT, woT);
  qkv_gemm<<<dim3(128, 6), 512, 0, stream>>>(xb, wT, qbuf, kbuf, vtbuf);
  attn<<<512, 256, 0, stream>>>(qbuf, kbuf, vtbuf, rel_row, rel_col, obuf);
  out_gemm<<<dim3(128, 2), 512, 0, stream>>>(obuf, woT, out);
}